// Round 4
// baseline (285.395 us; speedup 1.0000x reference)
//
#include <hip/hip_runtime.h>

// EquivariantCombination (iro=1, fro=1) on MI355X.
// Inputs:  tensor [B=256][F=64][3] fp32, f [A=1024][B=256][F=64][3] fp32
// Outputs: o0 [A][F][1] then o1 [A][F][3], concatenated flat in d_out (fp32).
//
// o0[a,fc]   = sum_b (sum_j f[a,b,fc,j]) * (sum_k tensor[b,fc,k])
// o1[a,fc,:] = sum_b cross(f[a,b,fc,:], tensor[b,fc,:])
//
// Memory-bound: f = 201 MB streamed once -> ~32 us floor @ 6.3 TB/s.
// One block per 'a' (1024 blocks = 4 blocks/CU, 256 thr = 16 waves/CU).
// Thread t: fc = t&63, bg = t>>6; loops b = bg..252 step 4, unroll 8.
// Wave = one fc-sweep at fixed b -> 64 lanes x 12 B contiguous = 768 B
// coalesced row read. LDS reduce across the 4 b-groups at the end.

#define A_DIM 1024
#define B_DIM 256
#define F_DIM 64

__global__ __launch_bounds__(256, 4) void equiv_comb_kernel(
    const float* __restrict__ tensor,   // [B][F][3]
    const float* __restrict__ f,        // [A][B][F][3]
    float* __restrict__ out)            // [A*F] o0, then [A*F*3] o1
{
    const int a  = blockIdx.x;
    const int t  = threadIdx.x;
    const int fc = t & 63;
    const int bg = t >> 6;              // 0..3

    const float* __restrict__ fbase = f + (size_t)a * (B_DIM * F_DIM * 3);

    float acc0 = 0.f, c0 = 0.f, c1 = 0.f, c2 = 0.f;

    // 64 iterations per thread; unroll 8 -> 8 x 12 B f-loads in flight.
    #pragma unroll 8
    for (int b = bg; b < B_DIM; b += 4) {
        const float* __restrict__ fp = fbase  + (size_t)b * (F_DIM * 3) + fc * 3;
        const float* __restrict__ tp = tensor + (size_t)b * (F_DIM * 3) + fc * 3;
        const float f0 = fp[0], f1 = fp[1], f2 = fp[2];
        const float t0 = tp[0], t1 = tp[1], t2 = tp[2];
        acc0 += (f0 + f1 + f2) * (t0 + t1 + t2);
        c0 += f1 * t2 - f2 * t1;
        c1 += f2 * t0 - f0 * t2;
        c2 += f0 * t1 - f1 * t0;
    }

    // Reduce the 4 b-groups through LDS.
    __shared__ float red[4][F_DIM][4];
    red[bg][fc][0] = acc0;
    red[bg][fc][1] = c0;
    red[bg][fc][2] = c1;
    red[bg][fc][3] = c2;
    __syncthreads();

    if (t < F_DIM) {
        float s0 = 0.f, s1 = 0.f, s2 = 0.f, s3 = 0.f;
        #pragma unroll
        for (int g = 0; g < 4; ++g) {
            s0 += red[g][t][0];
            s1 += red[g][t][1];
            s2 += red[g][t][2];
            s3 += red[g][t][3];
        }
        out[a * F_DIM + t] = s0;                                   // o0
        float* __restrict__ o1 = out + A_DIM * F_DIM + (size_t)(a * F_DIM + t) * 3;
        o1[0] = s1;
        o1[1] = s2;
        o1[2] = s3;
    }
}

extern "C" void kernel_launch(void* const* d_in, const int* in_sizes, int n_in,
                              void* d_out, int out_size, void* d_ws, size_t ws_size,
                              hipStream_t stream) {
    const float* tensor = (const float*)d_in[0];   // [B,F,3]
    const float* f      = (const float*)d_in[1];   // [A,B,F,3]
    float* out          = (float*)d_out;           // 65536 + 196608 floats

    equiv_comb_kernel<<<dim3(A_DIM), dim3(256), 0, stream>>>(tensor, f, out);
}

// Round 9
// 279.231 us; speedup vs baseline: 1.0221x; 1.0221x over previous
//
#include <hip/hip_runtime.h>

// EquivariantCombination (iro=1, fro=1) on MI355X.
// Inputs:  tensor [B=256][F=64][3] fp32, f [A=1024][B=256][F=64][3] fp32
// Outputs: o0 [A][F][1] then o1 [A][F][3], concatenated flat in d_out (fp32).
//
// o0[a,fc]   = sum_b (sum_j f[a,b,fc,j]) * (sum_k tensor[b,fc,k])
// o1[a,fc,:] = sum_b cross(f[a,b,fc,:], tensor[b,fc,:])
//
// Memory-bound: f = 201 MB streamed once -> ~32 us floor @ 6.3 TB/s.
// One block per 'a' (1024 blocks = 4/CU, 256 thr = 16 waves/CU).
// Thread t: fcg = t&15 (4 consecutive feature channels = 12 contiguous
// floats = 3 aligned float4), bslot = t>>4; b = bslot + 16k, k=0..15.
// All f/tensor traffic is aligned 16B vector loads (m13 streaming idiom);
// f loads nontemporal via clang ext_vector type (HIP float4 struct is
// rejected by the builtin). Compute fully lane-local; LDS reduce
// (stride-5 padded, conflict-free) only in the epilogue.

#define A_DIM 1024
#define B_DIM 256
#define F_DIM 64

typedef float f32x4 __attribute__((ext_vector_type(4)));

__global__ __launch_bounds__(256, 4) void equiv_comb_kernel(
    const float* __restrict__ tensor,   // [B][F][3]
    const float* __restrict__ f,        // [A][B][F][3]
    float* __restrict__ out)            // [A*F] o0, then [A*F*3] o1
{
    const int a     = blockIdx.x;
    const int t     = threadIdx.x;
    const int fcg   = t & 15;           // feature-channel group of 4
    const int bslot = t >> 4;           // 0..15

    const float* __restrict__ fbase = f + (size_t)a * (B_DIM * F_DIM * 3);

    float a0[4] = {0.f, 0.f, 0.f, 0.f};
    float cx[4] = {0.f, 0.f, 0.f, 0.f};
    float cy[4] = {0.f, 0.f, 0.f, 0.f};
    float cz[4] = {0.f, 0.f, 0.f, 0.f};

    #pragma unroll 2
    for (int k = 0; k < 16; ++k) {
        const int b = bslot + (k << 4);
        const f32x4* __restrict__ fp =
            reinterpret_cast<const f32x4*>(fbase  + (size_t)b * (F_DIM * 3) + fcg * 12);
        const f32x4* __restrict__ tp =
            reinterpret_cast<const f32x4*>(tensor + (size_t)b * (F_DIM * 3) + fcg * 12);

        const f32x4 fl0 = __builtin_nontemporal_load(fp + 0);
        const f32x4 fl1 = __builtin_nontemporal_load(fp + 1);
        const f32x4 fl2 = __builtin_nontemporal_load(fp + 2);
        const f32x4 tl0 = tp[0];
        const f32x4 tl1 = tp[1];
        const f32x4 tl2 = tp[2];

        const float fv[12] = {fl0.x, fl0.y, fl0.z, fl0.w,
                              fl1.x, fl1.y, fl1.z, fl1.w,
                              fl2.x, fl2.y, fl2.z, fl2.w};
        const float tv[12] = {tl0.x, tl0.y, tl0.z, tl0.w,
                              tl1.x, tl1.y, tl1.z, tl1.w,
                              tl2.x, tl2.y, tl2.z, tl2.w};

        #pragma unroll
        for (int q = 0; q < 4; ++q) {
            const float f0 = fv[q * 3 + 0], f1 = fv[q * 3 + 1], f2 = fv[q * 3 + 2];
            const float t0 = tv[q * 3 + 0], t1 = tv[q * 3 + 1], t2 = tv[q * 3 + 2];
            a0[q] += (f0 + f1 + f2) * (t0 + t1 + t2);
            cx[q] += f1 * t2 - f2 * t1;
            cy[q] += f2 * t0 - f0 * t2;
            cz[q] += f0 * t1 - f1 * t0;
        }
    }

    // Cross-bslot reduction through LDS. Stride 5 -> bank-conflict-free.
    __shared__ float red[16][F_DIM][5];
    #pragma unroll
    for (int q = 0; q < 4; ++q) {
        const int fc = fcg * 4 + q;
        red[bslot][fc][0] = a0[q];
        red[bslot][fc][1] = cx[q];
        red[bslot][fc][2] = cy[q];
        red[bslot][fc][3] = cz[q];
    }
    __syncthreads();

    if (t < F_DIM) {
        float s0 = 0.f, s1 = 0.f, s2 = 0.f, s3 = 0.f;
        #pragma unroll
        for (int s = 0; s < 16; ++s) {
            s0 += red[s][t][0];
            s1 += red[s][t][1];
            s2 += red[s][t][2];
            s3 += red[s][t][3];
        }
        out[a * F_DIM + t] = s0;                                   // o0
        float* __restrict__ o1 = out + A_DIM * F_DIM + (size_t)(a * F_DIM + t) * 3;
        o1[0] = s1;
        o1[1] = s2;
        o1[2] = s3;
    }
}

extern "C" void kernel_launch(void* const* d_in, const int* in_sizes, int n_in,
                              void* d_out, int out_size, void* d_ws, size_t ws_size,
                              hipStream_t stream) {
    const float* tensor = (const float*)d_in[0];   // [B,F,3]
    const float* f      = (const float*)d_in[1];   // [A,B,F,3]
    float* out          = (float*)d_out;           // 65536 + 196608 floats

    equiv_comb_kernel<<<dim3(A_DIM), dim3(256), 0, stream>>>(tensor, f, out);
}